// Round 14
// baseline (674.661 us; speedup 1.0000x reference)
//
#include <hip/hip_runtime.h>
#include <math.h>

#define DEV __device__ __forceinline__

constexpr int B = 4, L = 200, SP = 225;
constexpr int C1 = 4, D1 = 200;
constexpr int C2N = 8, D2 = 100;
constexpr int C3N = 4, D3 = 50;
constexpr int D4 = 25;
constexpr float EPS = 1e-5f;

// ---- workspace layout (float offsets) ----
constexpr size_t OFF_F1  = 0;                      // B*C1*D1*SP raw
constexpr size_t OFF_E2  = OFF_F1  + 720000;       // raw; REUSED as fc1T (90000) after k_T2
constexpr size_t OFF_E1  = OFF_E2  + 720000;
constexpr size_t OFF_SS1 = OFF_E1  + 720000;       // 6*3200
constexpr size_t OFF_PAR = OFF_SS1 + 19200;        // 1024 params
constexpr size_t OFF_F2  = OFF_PAR + 1024;         // raw
constexpr size_t OFF_C2  = OFF_F2  + 720000;       // C2N*SP raw
constexpr size_t OFF_T2  = OFF_C2  + 1800;         // raw
constexpr size_t OFF_SS2F= OFF_T2  + 2880000;
constexpr size_t OFF_SS2T= OFF_SS2F+ 6400;
constexpr size_t OFF_SS2C= OFF_SS2T+ 51200;
constexpr size_t OFF_F3  = OFF_SS2C+ 16;
constexpr size_t OFF_C3  = OFF_F3  + 180000;
constexpr size_t OFF_T3  = OFF_C3  + 900;
constexpr size_t OFF_SS3F= OFF_T3  + 1440000;
constexpr size_t OFF_SS3T= OFF_SS3F+ 1600;
constexpr size_t OFF_SS3C= OFF_SS3T+ 12800;
constexpr size_t OFF_F4  = OFF_SS3C+ 8;
constexpr size_t OFF_C4  = OFF_F4  + 22500;
constexpr size_t OFF_T4  = OFF_C4  + 225;
constexpr size_t OFF_SS4F= OFF_T4  + 360000;
constexpr size_t OFF_SS4T= OFF_SS4F+ 200;
constexpr size_t OFF_SS4C= OFF_SS4T+ 3200;
constexpr size_t OFF_Z   = OFF_SS4C+ 2;            // B*L*25*SP
constexpr size_t OFF_CB  = OFF_Z   + 4500000;
constexpr size_t OFF_P2D = OFF_CB  + 4500000;      // 800*25*2
constexpr size_t WS_FLOATS = OFF_P2D + 40000;

// params: 0..3 sc1, 4..7 sh1, 8..11 z1; 16..23 sc2, 24..31 sh2;
// 32..35 sc3, 36..39 sh3; 40 sc4, 41 sh4; 48..72 sc2d, 80..104 sh2d

DEV float waveRed(float v) {
    #pragma unroll
    for (int m = 32; m; m >>= 1) v += __shfl_xor(v, m, 64);
    return v;
}
DEV double blockSumD(double v, double* red) {
    int tid = threadIdx.x;
    red[tid] = v; __syncthreads();
    for (int s = 128; s > 0; s >>= 1) { if (tid < s) red[tid] += red[tid + s]; __syncthreads(); }
    double r = red[0]; __syncthreads(); return r;
}
DEV float conv9(const float* S, const float* w, int y, int x) {
    float a = 0.f;
    for (int ky = 0; ky < 3; ky++) { int yy = y + ky - 1; if (yy < 0 || yy >= 15) continue;
        for (int kx = 0; kx < 3; kx++) { int xx = x + kx - 1; if (xx < 0 || xx >= 15) continue;
            a += w[ky * 3 + kx] * S[yy * 15 + xx]; } }
    return a;
}
// gather 9-neighborhood of (y,x) from a 15x15 LDS plane into regs
DEV void gather9(const float* Sp, int y, int x, float* s9) {
    #pragma unroll
    for (int ky = 0; ky < 3; ky++) {
        int yy = y + ky - 1; bool oky = (yy >= 0 && yy < 15);
        #pragma unroll
        for (int kx = 0; kx < 3; kx++) {
            int xx = x + kx - 1; bool ok = oky && (xx >= 0 && xx < 15);
            s9[ky * 3 + kx] = ok ? Sp[yy * 15 + xx] : 0.f;
        }
    }
}

// ---------------- layer 1: all 4 channels per block ----------------
__global__ __launch_bounds__(256) void k_layer1(const int* __restrict__ xi, const float* __restrict__ emb,
                        const float* __restrict__ w3a, float* F1, float* E2, float* E1, float* SS1) {
    __shared__ float simg[675];
    __shared__ float wl[108];
    __shared__ float red[96];   // wave(4) x c(4) x 6
    int blk = blockIdx.x;
    int d = blk % D1; int b = blk / D1;
    int tid = threadIdx.x;
    if (tid < 108) wl[tid] = w3a[tid];
    for (int idx = tid; idx < 675; idx += 256) {
        int t = idx / 225, pos = idx % 225;
        int j = d + t - 1; float v = 0.f;
        if (j >= 0 && j < L) v = emb[(size_t)xi[b * L + j] * SP + pos];
        simg[idx] = v;
    }
    __syncthreads();
    int y = tid / 15, x = tid % 15;
    int w = tid >> 6;
    #pragma unroll 1
    for (int c = 0; c < 4; c++) {
        float f1 = 0.f, e2 = 0.f, e1 = 0.f;
        if (tid < 225) {
            float P0 = conv9(simg,       wl + c * 27,      y, x);
            float P1 = conv9(simg + 225, wl + c * 27 + 9,  y, x);
            float P2 = conv9(simg + 450, wl + c * 27 + 18, y, x);
            f1 = P0 + P1 + P2; e2 = P0 + P1; e1 = P0;
            size_t o = ((size_t)(b * C1 + c) * D1 + d) * SP + tid;
            F1[o] = f1; E2[o] = e2; E1[o] = e1;
        }
        float r0 = waveRed(f1), r1 = waveRed(f1 * f1), r2 = waveRed(e2),
              r3 = waveRed(e2 * e2), r4 = waveRed(e1), r5 = waveRed(e1 * e1);
        if ((tid & 63) == 0) {
            float* rp = red + w * 24 + c * 6;
            rp[0] = r0; rp[1] = r1; rp[2] = r2; rp[3] = r3; rp[4] = r4; rp[5] = r5;
        }
    }
    __syncthreads();
    if (tid < 24) {
        float s = red[tid] + red[24 + tid] + red[48 + tid] + red[72 + tid];
        int c = tid / 6, q = tid % 6;
        SS1[q * 3200 + (b * C1 + c) * D1 + d] = s;
    }
}

__global__ void k_stats1(const float* SS1, const float* g, const float* bb, float* par) {
    __shared__ double dred[256];
    int c = blockIdx.x; int tid = threadIdx.x;
    double s = 0, q = 0;
    for (int idx = tid; idx < B * D1; idx += 256) {
        int b = idx / D1, d = idx % D1;
        int sl = (b * C1 + c) * D1 + d;
        double wF = (double)(L - 1 - d);
        s += wF * SS1[sl] + SS1[6400 + sl] + (d >= 1 ? SS1[12800 + sl] : 0.0);
        q += wF * SS1[3200 + sl] + SS1[9600 + sl] + (d >= 1 ? SS1[16000 + sl] : 0.0);
    }
    s = blockSumD(s, dred); q = blockSumD(q, dred);
    if (tid == 0) {
        double N = (double)B * L * D1 * SP;
        double mean = s / N, var = q / N - mean * mean;
        float sc = g[c] / (float)sqrt(var + (double)EPS);
        float sh = bb[c] - (float)mean * sc;
        par[c] = sc; par[4 + c] = sh; par[8 + c] = fmaxf(sh, 0.f);
    }
}

// ---------------- layer 2 ----------------
__global__ __launch_bounds__(256) void k_F2(const float* __restrict__ F1raw, const float* __restrict__ par,
                        const float* __restrict__ w3b, float* F2, float* SS2F) {
    __shared__ float S[2700];   // [t][c][225]
    __shared__ float wl[108];
    __shared__ float red[8];
    int blk = blockIdx.x; int d2 = blk % D2; int c2 = (blk / D2) % C2N; int b = blk / (D2 * C2N);
    int tid = threadIdx.x;
    if (tid < 108) wl[tid] = w3b[c2 * 108 + tid];
    for (int idx = tid; idx < 2700; idx += 256) {
        int p = idx / 225, pos = idx % 225; int t = p >> 2, c = p & 3;
        int j = 2 * d2 - 1 + t; float v = 0.f;
        if (j >= 0 && j < D1)
            v = fmaxf(par[c] * F1raw[((size_t)(b * C1 + c) * D1 + j) * SP + pos] + par[4 + c], 0.f);
        S[idx] = v;
    }
    __syncthreads();
    float acc = 0.f;
    if (tid < 225) {
        int y = tid / 15, x = tid % 15;
        #pragma unroll 1
        for (int t = 0; t < 3; t++)
            for (int c = 0; c < 4; c++)
                acc += conv9(S + (t * 4 + c) * 225, wl + c * 27 + t * 9, y, x);
        F2[(size_t)blk * SP + tid] = acc;
    }
    float sm = waveRed(acc), sq = waveRed(acc * acc);
    if ((tid & 63) == 0) { red[(tid >> 6) * 2] = sm; red[(tid >> 6) * 2 + 1] = sq; }
    __syncthreads();
    if (tid == 0) { SS2F[blk] = red[0] + red[2] + red[4] + red[6]; SS2F[3200 + blk] = red[1] + red[3] + red[5] + red[7]; }
}

__global__ void k_C2(const float* __restrict__ par, const float* __restrict__ w3b, float* C2b, float* SS2C) {
    __shared__ float red[64];   // wave(4) x c2(8) x 2
    int tid = threadIdx.x; int y = tid / 15, x = tid % 15; int w = tid >> 6;
    #pragma unroll 1
    for (int c2 = 0; c2 < C2N; c2++) {
        float acc = 0.f;
        if (tid < 225) {
            for (int c = 0; c < C1; c++) {
                float z1 = par[8 + c];
                for (int t = 0; t < 3; t++) {
                    float ws = 0.f;
                    for (int ky = 0; ky < 3; ky++) { int yy = y + ky - 1; if (yy < 0 || yy >= 15) continue;
                        for (int kx = 0; kx < 3; kx++) { int xx = x + kx - 1; if (xx < 0 || xx >= 15) continue;
                            ws += w3b[c2 * 108 + c * 27 + t * 9 + ky * 3 + kx]; } }
                    acc += z1 * ws;
                }
            }
            C2b[c2 * SP + tid] = acc;
        }
        float sm = waveRed(acc), sq = waveRed(acc * acc);
        if ((tid & 63) == 0) { red[w * 16 + c2 * 2] = sm; red[w * 16 + c2 * 2 + 1] = sq; }
    }
    __syncthreads();
    if (tid < 16) SS2C[tid] = red[tid] + red[16 + tid] + red[32 + tid] + red[48 + tid];
}

// 512 threads: group g=tid>>8 computes transition k=g; weights from global (L1/K$).
__global__ __launch_bounds__(512) void k_T2(const float* __restrict__ F1raw, const float* __restrict__ E2raw,
                    const float* __restrict__ E1raw, const float* __restrict__ par,
                    const float* __restrict__ w3b, float* T2, float* SS2T) {
    __shared__ float S[4500];   // [sl 0..4][c 0..3][225]
    __shared__ float red[128];  // 8 waves x 8 c2 x 2
    int blk = blockIdx.x; int i = blk % L, b = blk / L; int tid = threadIdx.x;
    int t2a = i >> 1, jbase = 2 * t2a - 1;
    for (int idx = tid; idx < 4500; idx += 512) {
        int p = idx / 225, pos = idx % 225; int sl = p >> 2, c = p & 3;
        int j = jbase + sl; float v = 0.f;
        if (j >= 0 && j < L) {
            if (j <= i - 1)      v = fmaxf(par[c] * F1raw[((size_t)(b * C1 + c) * D1 + j) * SP + pos] + par[4 + c], 0.f);
            else if (j == i)     v = fmaxf(par[c] * E2raw[((size_t)(b * C1 + c) * D1 + j) * SP + pos] + par[4 + c], 0.f);
            else if (j == i + 1) v = fmaxf(par[c] * E1raw[((size_t)(b * C1 + c) * D1 + j) * SP + pos] + par[4 + c], 0.f);
            else                 v = par[8 + c];
        }
        S[idx] = v;
    }
    __syncthreads();
    int g = tid >> 8;            // k = g
    int tp = tid & 255;
    int y = tp / 15, x = tp % 15;
    float vals[8] = {0,0,0,0,0,0,0,0};
    int d2 = t2a + g;
    if (d2 < D2 && tp < 225) {
        #pragma unroll 1
        for (int t = 0; t < 3; t++) {
            int sl = 2 * g + t;
            #pragma unroll 1
            for (int c = 0; c < 4; c++) {
                float s9[9];
                gather9(S + (sl * 4 + c) * 225, y, x, s9);
                const float* wb = w3b + c * 27 + t * 9;   // uniform -> s_load
                #pragma unroll
                for (int c2 = 0; c2 < 8; c2++) {
                    const float* wc = wb + c2 * 108;
                    float a = 0.f;
                    #pragma unroll
                    for (int q = 0; q < 9; q++) a += wc[q] * s9[q];
                    vals[c2] += a;
                }
            }
        }
    }
    if (tp < 225)
        #pragma unroll
        for (int c2 = 0; c2 < 8; c2++) T2[(((size_t)blk * 2 + g) * C2N + c2) * SP + tp] = vals[c2];
    int w = tid >> 6;   // 0..7
    #pragma unroll
    for (int c2 = 0; c2 < 8; c2++) {
        float sm = waveRed(tp < 225 ? vals[c2] : 0.f), sq = waveRed(tp < 225 ? vals[c2] * vals[c2] : 0.f);
        if ((tid & 63) == 0) { red[w * 16 + c2 * 2] = sm; red[w * 16 + c2 * 2 + 1] = sq; }
    }
    __syncthreads();
    if (tid < 32) {
        int k = tid >> 4, idx = tid & 15;
        int c2 = idx >> 1, q = idx & 1;
        int wb = k * 4;
        float s = red[(wb + 0) * 16 + idx] + red[(wb + 1) * 16 + idx]
                + red[(wb + 2) * 16 + idx] + red[(wb + 3) * 16 + idx];
        (q ? SS2T + 25600 : SS2T)[((size_t)blk * 2 + k) * C2N + c2] = s;
    }
}

// closed-form multiplicities: F slice (b,d2) counted (L-2*d2-2)x; T entries once each
// (invalid entries are exact zeros); C counted sum_i max(0, D2-(i>>1)-2) per b.
__global__ void k_stats2(const float* SS2F, const float* SS2T, const float* SS2C,
                         const float* g, const float* bb, float* par) {
    __shared__ double dred[256];
    int c2 = blockIdx.x; int tid = threadIdx.x;
    double s = 0, q = 0;
    for (int idx = tid; idx < B * D2; idx += 256) {
        int d2 = idx % D2; int b = idx / D2;
        int wv = L - 2 * d2 - 2; if (wv < 0) wv = 0;
        int sl = (b * C2N + c2) * D2 + d2;
        s += (double)wv * SS2F[sl]; q += (double)wv * SS2F[3200 + sl];
    }
    for (int idx = tid; idx < B * L * 2; idx += 256) {
        int sl = idx * C2N + c2;
        s += SS2T[sl]; q += SS2T[25600 + sl];
    }
    {
        int cnt = 0;
        for (int i = tid; i < L; i += 256) { int v = D2 - (i >> 1) - 2; if (v > 0) cnt += v; }
        double wv = (double)cnt * B;
        s += wv * SS2C[c2 * 2]; q += wv * SS2C[c2 * 2 + 1];
    }
    s = blockSumD(s, dred); q = blockSumD(q, dred);
    if (tid == 0) {
        double N = (double)B * L * D2 * SP;
        double mean = s / N, var = q / N - mean * mean;
        float sc = g[c2] / (float)sqrt(var + (double)EPS);
        float sh = bb[c2] - (float)mean * sc;
        par[16 + c2] = sc; par[24 + c2] = sh;
    }
}

// ---------------- layer 3 ----------------
__global__ __launch_bounds__(256) void k_F3(const float* __restrict__ F2raw, const float* __restrict__ par,
                        const float* __restrict__ w3c, float* F3, float* SS3F) {
    __shared__ float S[5400];   // [t][c2][225]
    __shared__ float wl[216];
    __shared__ float red[8];
    int blk = blockIdx.x; int d3 = blk % D3; int c3 = (blk / D3) % C3N; int b = blk / (D3 * C3N);
    int tid = threadIdx.x;
    if (tid < 216) wl[tid] = w3c[c3 * 216 + tid];
    for (int idx = tid; idx < 5400; idx += 256) {
        int p = idx / 225, pos = idx % 225; int t = p >> 3, c2 = p & 7;
        int j2 = 2 * d3 - 1 + t; float v = 0.f;
        if (j2 >= 0 && j2 < D2)
            v = fmaxf(par[16 + c2] * F2raw[((size_t)(b * C2N + c2) * D2 + j2) * SP + pos] + par[24 + c2], 0.f);
        S[idx] = v;
    }
    __syncthreads();
    float acc = 0.f;
    if (tid < 225) {
        int y = tid / 15, x = tid % 15;
        #pragma unroll 1
        for (int t = 0; t < 3; t++)
            for (int c2 = 0; c2 < 8; c2++)
                acc += conv9(S + (t * 8 + c2) * 225, wl + c2 * 27 + t * 9, y, x);
        F3[(size_t)blk * SP + tid] = acc;
    }
    float sm = waveRed(acc), sq = waveRed(acc * acc);
    if ((tid & 63) == 0) { red[(tid >> 6) * 2] = sm; red[(tid >> 6) * 2 + 1] = sq; }
    __syncthreads();
    if (tid == 0) { SS3F[blk] = red[0] + red[2] + red[4] + red[6]; SS3F[800 + blk] = red[1] + red[3] + red[5] + red[7]; }
}

__global__ void k_C3(const float* __restrict__ C2braw, const float* __restrict__ par,
                     const float* __restrict__ w3c, float* C3b, float* SS3C) {
    __shared__ float S[1800];
    __shared__ float red[32];   // wave(4) x c3(4) x 2
    int tid = threadIdx.x; int w = tid >> 6;
    for (int idx = tid; idx < 1800; idx += 256) {
        int c2 = idx / 225;
        S[idx] = fmaxf(par[16 + c2] * C2braw[idx] + par[24 + c2], 0.f);
    }
    __syncthreads();
    int y = tid / 15, x = tid % 15;
    #pragma unroll 1
    for (int c3 = 0; c3 < C3N; c3++) {
        float acc = 0.f;
        if (tid < 225) {
            for (int t = 0; t < 3; t++)
                for (int c2 = 0; c2 < C2N; c2++)
                    acc += conv9(S + c2 * 225, w3c + c3 * 216 + c2 * 27 + t * 9, y, x);
            C3b[c3 * SP + tid] = acc;
        }
        float sm = waveRed(acc), sq = waveRed(acc * acc);
        if ((tid & 63) == 0) { red[w * 8 + c3 * 2] = sm; red[w * 8 + c3 * 2 + 1] = sq; }
    }
    __syncthreads();
    if (tid < 8) SS3C[tid] = red[tid] + red[8 + tid] + red[16 + tid] + red[24 + tid];
}

// 512 threads: group g=tid>>8 computes transition k=g; weights from global (L1/K$).
__global__ __launch_bounds__(512) void k_T3(const float* __restrict__ F2raw, const float* __restrict__ T2raw,
                    const float* __restrict__ C2braw, const float* __restrict__ par,
                    const float* __restrict__ w3c, float* T3, float* SS3T) {
    __shared__ float S[9000];   // [sl 0..4][c2 0..7][225]
    __shared__ float red[64];   // 8 waves x 4 c3 x 2
    int blk = blockIdx.x; int i = blk % L, b = blk / L; int tid = threadIdx.x;
    int t2a = i >> 1, t3a = i >> 2, j2base = 2 * t3a - 1;
    for (int idx = tid; idx < 9000; idx += 512) {
        int p = idx / 225, pos = idx % 225; int sl = p >> 3, c2 = p & 7;
        int j2 = j2base + sl; float v = 0.f;
        if (j2 >= 0 && j2 < D2) {
            float raw;
            if (j2 < t2a)           raw = F2raw[((size_t)(b * C2N + c2) * D2 + j2) * SP + pos];
            else if (j2 == t2a)     raw = T2raw[(((size_t)blk * 2 + 0) * C2N + c2) * SP + pos];
            else if (j2 == t2a + 1) raw = T2raw[(((size_t)blk * 2 + 1) * C2N + c2) * SP + pos];
            else                    raw = C2braw[c2 * SP + pos];
            v = fmaxf(par[16 + c2] * raw + par[24 + c2], 0.f);
        }
        S[idx] = v;
    }
    __syncthreads();
    int g = tid >> 8;            // k = g
    int tp = tid & 255;
    int y = tp / 15, x = tp % 15;
    float vals[4] = {0, 0, 0, 0};
    int d3 = t3a + g;
    if (d3 < D3 && tp < 225) {
        #pragma unroll 1
        for (int t = 0; t < 3; t++) {
            int sl = 2 * g + t;
            #pragma unroll 1
            for (int c2 = 0; c2 < 8; c2++) {
                float s9[9];
                gather9(S + (sl * 8 + c2) * 225, y, x, s9);
                const float* wb = w3c + c2 * 27 + t * 9;   // uniform -> s_load
                #pragma unroll
                for (int c3 = 0; c3 < 4; c3++) {
                    const float* wc = wb + c3 * 216;
                    float a = 0.f;
                    #pragma unroll
                    for (int q = 0; q < 9; q++) a += wc[q] * s9[q];
                    vals[c3] += a;
                }
            }
        }
    }
    if (tp < 225)
        #pragma unroll
        for (int c3 = 0; c3 < 4; c3++) T3[(((size_t)blk * 2 + g) * C3N + c3) * SP + tp] = vals[c3];
    int w = tid >> 6;   // 0..7
    #pragma unroll
    for (int c3 = 0; c3 < 4; c3++) {
        float sm = waveRed(tp < 225 ? vals[c3] : 0.f), sq = waveRed(tp < 225 ? vals[c3] * vals[c3] : 0.f);
        if ((tid & 63) == 0) { red[w * 8 + c3 * 2] = sm; red[w * 8 + c3 * 2 + 1] = sq; }
    }
    __syncthreads();
    if (tid < 16) {
        int k = tid >> 3, idx = tid & 7;
        int c3 = idx >> 1, q = idx & 1;
        int wb = k * 4;
        float s = red[(wb + 0) * 8 + idx] + red[(wb + 1) * 8 + idx]
                + red[(wb + 2) * 8 + idx] + red[(wb + 3) * 8 + idx];
        (q ? SS3T + 6400 : SS3T)[((size_t)blk * 2 + k) * C3N + c3] = s;
    }
}

__global__ void k_stats3(const float* SS3F, const float* SS3T, const float* SS3C,
                         const float* g, const float* bb, float* par) {
    __shared__ double dred[256];
    int c3 = blockIdx.x; int tid = threadIdx.x;
    double s = 0, q = 0;
    for (int idx = tid; idx < B * D3; idx += 256) {
        int d3 = idx % D3; int b = idx / D3;
        int wv = L - 4 * d3 - 4; if (wv < 0) wv = 0;
        int sl = (b * C3N + c3) * D3 + d3;
        s += (double)wv * SS3F[sl]; q += (double)wv * SS3F[800 + sl];
    }
    for (int idx = tid; idx < B * L * 2; idx += 256) {
        int sl = idx * C3N + c3;
        s += SS3T[sl]; q += SS3T[6400 + sl];
    }
    {
        int cnt = 0;
        for (int i = tid; i < L; i += 256) { int v = D3 - (i >> 2) - 2; if (v > 0) cnt += v; }
        double wv = (double)cnt * B;
        s += wv * SS3C[c3 * 2]; q += wv * SS3C[c3 * 2 + 1];
    }
    s = blockSumD(s, dred); q = blockSumD(q, dred);
    if (tid == 0) {
        double N = (double)B * L * D3 * SP;
        double mean = s / N, var = q / N - mean * mean;
        float sc = g[c3] / (float)sqrt(var + (double)EPS);
        float sh = bb[c3] - (float)mean * sc;
        par[32 + c3] = sc; par[36 + c3] = sh;
    }
}

// ---------------- layer 4 ----------------
__global__ __launch_bounds__(256) void k_F4(const float* __restrict__ F3raw, const float* __restrict__ par,
                        const float* __restrict__ w3d, float* F4, float* SS4F) {
    __shared__ float S[2700];   // [t][c3][225]
    __shared__ float wl[108];
    __shared__ float red[8];
    int blk = blockIdx.x; int d4 = blk % D4; int b = blk / D4; int tid = threadIdx.x;
    if (tid < 108) wl[tid] = w3d[tid];
    for (int idx = tid; idx < 2700; idx += 256) {
        int p = idx / 225, pos = idx % 225; int t = p >> 2, c3 = p & 3;
        int j3 = 2 * d4 - 1 + t; float v = 0.f;
        if (j3 >= 0 && j3 < D3)
            v = fmaxf(par[32 + c3] * F3raw[((size_t)(b * C3N + c3) * D3 + j3) * SP + pos] + par[36 + c3], 0.f);
        S[idx] = v;
    }
    __syncthreads();
    float acc = 0.f;
    if (tid < 225) {
        int y = tid / 15, x = tid % 15;
        #pragma unroll 1
        for (int t = 0; t < 3; t++)
            for (int c3 = 0; c3 < 4; c3++)
                acc += conv9(S + (t * 4 + c3) * 225, wl + c3 * 27 + t * 9, y, x);
        F4[(size_t)blk * SP + tid] = acc;
    }
    float sm = waveRed(acc), sq = waveRed(acc * acc);
    if ((tid & 63) == 0) { red[(tid >> 6) * 2] = sm; red[(tid >> 6) * 2 + 1] = sq; }
    __syncthreads();
    if (tid == 0) { SS4F[blk] = red[0] + red[2] + red[4] + red[6]; SS4F[100 + blk] = red[1] + red[3] + red[5] + red[7]; }
}

__global__ void k_C4(const float* __restrict__ C3braw, const float* __restrict__ par,
                     const float* __restrict__ w3d, float* C4b, float* SS4C) {
    __shared__ float S[900];
    __shared__ float red[8];
    int tid = threadIdx.x;
    for (int idx = tid; idx < 900; idx += 256) {
        int c3 = idx / 225;
        S[idx] = fmaxf(par[32 + c3] * C3braw[idx] + par[36 + c3], 0.f);
    }
    __syncthreads();
    int y = tid / 15, x = tid % 15;
    float acc = 0.f;
    if (tid < 225) {
        for (int t = 0; t < 3; t++)
            for (int c3 = 0; c3 < C3N; c3++)
                acc += conv9(S + c3 * 225, w3d + c3 * 27 + t * 9, y, x);
        C4b[tid] = acc;
    }
    float sm = waveRed(acc), sq = waveRed(acc * acc);
    if ((tid & 63) == 0) { red[(tid >> 6) * 2] = sm; red[(tid >> 6) * 2 + 1] = sq; }
    __syncthreads();
    if (tid == 0) { SS4C[0] = red[0] + red[2] + red[4] + red[6]; SS4C[1] = red[1] + red[3] + red[5] + red[7]; }
}

// 512 threads: group g=tid>>8 computes transition k=g; weights from global (L1/K$).
__global__ __launch_bounds__(512) void k_T4(const float* __restrict__ F3raw, const float* __restrict__ T3raw,
                    const float* __restrict__ C3braw, const float* __restrict__ par,
                    const float* __restrict__ w3d, float* T4, float* SS4T) {
    __shared__ float S[4500];   // [sl][c3][225]
    __shared__ float red[16];   // 8 waves x 2
    int blk = blockIdx.x; int i = blk % L, b = blk / L; int tid = threadIdx.x;
    int t3a = i >> 2, t4a = i >> 3, j3base = 2 * t4a - 1;
    for (int idx = tid; idx < 4500; idx += 512) {
        int p = idx / 225, pos = idx % 225; int sl = p >> 2, c3 = p & 3;
        int j3 = j3base + sl; float v = 0.f;
        if (j3 >= 0 && j3 < D3) {
            float raw;
            if (j3 < t3a)           raw = F3raw[((size_t)(b * C3N + c3) * D3 + j3) * SP + pos];
            else if (j3 == t3a)     raw = T3raw[(((size_t)blk * 2 + 0) * C3N + c3) * SP + pos];
            else if (j3 == t3a + 1) raw = T3raw[(((size_t)blk * 2 + 1) * C3N + c3) * SP + pos];
            else                    raw = C3braw[c3 * SP + pos];
            v = fmaxf(par[32 + c3] * raw + par[36 + c3], 0.f);
        }
        S[idx] = v;
    }
    __syncthreads();
    int g = tid >> 8;            // k = g
    int tp = tid & 255;
    int y = tp / 15, x = tp % 15;
    float acc = 0.f;
    int d4 = t4a + g;
    if (d4 < D4 && tp < 225) {
        #pragma unroll 1
        for (int t = 0; t < 3; t++) {
            int sl = 2 * g + t;
            #pragma unroll 1
            for (int c3 = 0; c3 < 4; c3++) {
                float s9[9];
                gather9(S + (sl * 4 + c3) * 225, y, x, s9);
                const float* wc = w3d + c3 * 27 + t * 9;   // uniform -> s_load
                float a = 0.f;
                #pragma unroll
                for (int q = 0; q < 9; q++) a += wc[q] * s9[q];
                acc += a;
            }
        }
    }
    if (tp < 225) T4[((size_t)blk * 2 + g) * SP + tp] = acc;
    int w = tid >> 6;
    float sm = waveRed(tp < 225 ? acc : 0.f), sq = waveRed(tp < 225 ? acc * acc : 0.f);
    if ((tid & 63) == 0) { red[w * 2] = sm; red[w * 2 + 1] = sq; }
    __syncthreads();
    if (tid < 4) {
        int k = tid >> 1, q = tid & 1;
        int wb = k * 4;
        float s = red[(wb + 0) * 2 + q] + red[(wb + 1) * 2 + q] + red[(wb + 2) * 2 + q] + red[(wb + 3) * 2 + q];
        (q ? SS4T + 1600 : SS4T)[blk * 2 + k] = s;
    }
}

__global__ void k_stats4(const float* SS4F, const float* SS4T, const float* SS4C,
                         const float* g, const float* bb, float* par) {
    __shared__ double dred[256];
    int tid = threadIdx.x; double s = 0, q = 0;
    for (int idx = tid; idx < B * D4; idx += 256) {
        int d4 = idx % D4; int b = idx / D4;
        int wv = L - 8 * d4 - 8; if (wv < 0) wv = 0;
        s += (double)wv * SS4F[b * D4 + d4]; q += (double)wv * SS4F[100 + b * D4 + d4];
    }
    for (int idx = tid; idx < B * L * 2; idx += 256) {
        s += SS4T[idx]; q += SS4T[1600 + idx];
    }
    {
        int cnt = 0;
        for (int i = tid; i < L; i += 256) { int v = D4 - (i >> 3) - 2; if (v > 0) cnt += v; }
        double wv = (double)cnt * B;
        s += wv * SS4C[0]; q += wv * SS4C[1];
    }
    s = blockSumD(s, dred); q = blockSumD(q, dred);
    if (tid == 0) {
        double N = (double)B * L * D4 * SP;
        double mean = s / N, var = q / N - mean * mean;
        float sc = g[0] / (float)sqrt(var + (double)EPS);
        float sh = bb[0] - (float)mean * sc;
        par[40] = sc; par[41] = sh;
    }
}

// ---------------- fc1 weight transpose (into dead E2 region) ----------------
__global__ void k_trfc1(const float* __restrict__ fc1w, float* __restrict__ fc1T) {
    int idx = blockIdx.x * 256 + threadIdx.x;
    if (idx >= 200 * 450) return;
    int o = idx % 200, k = idx / 200;
    fc1T[idx] = fc1w[(size_t)o * 450 + k];
}

// ---------------- 2D residual conv loop ----------------
// 768 threads: thread=(c2,y,xhalf) -> 750 active, 12 waves/block (2x r12).
// half0: cols 0..7, half1: cols 7..14 (col 7 dup, identical; excluded from half1 sums).
// Weights from global via L1 (r12 proven). Single block per sample -> no races.
template<int MODE>
__global__ __launch_bounds__(768) void k_conv2d(const float* __restrict__ zin, float* __restrict__ zout,
        const float* __restrict__ cprev, const float* __restrict__ par,
        const float* __restrict__ F4s, const float* __restrict__ T4s, const float* __restrict__ C4s,
        const float* __restrict__ w2it, float* __restrict__ cbuf, float* __restrict__ part) {
    __shared__ float zs[5625];    // unpadded: stride 15 -> conflict-free
    __shared__ float rowsum[750], rowsq[750];
    int s = blockIdx.x, tid = threadIdx.x;
    int i = s % L, b = s / L; int t4a = i >> 3;
    for (int idx = tid; idx < 5625; idx += 768) {
        int c = idx / 225, pos = idx % 225;
        float v;
        if (MODE == 0) {
            float raw;
            if (c < t4a)           raw = F4s[((size_t)b * D4 + c) * SP + pos];
            else if (c == t4a)     raw = T4s[((size_t)s * 2 + 0) * SP + pos];
            else if (c == t4a + 1) raw = T4s[((size_t)s * 2 + 1) * SP + pos];
            else                   raw = C4s[pos];
            v = fmaxf(par[40] * raw + par[41], 0.f);
        } else {
            v = zin[(size_t)s * 5625 + idx] + fmaxf(par[48 + c] * cprev[(size_t)s * 5625 + idx] + par[80 + c], 0.f);
        }
        zout[(size_t)s * 5625 + idx] = v;
        zs[idx] = v;
    }
    __syncthreads();
    if (tid < 750) {
        int c2 = tid / 30, r = tid % 30;
        int y = r >> 1, xh = r & 1;
        int xb = xh * 7;          // half0 cols 0..7, half1 cols 7..14
        float acc[8];
        #pragma unroll
        for (int xx = 0; xx < 8; xx++) acc[xx] = 0.f;
        const float* wrow = w2it + c2 * 225;
        #pragma unroll 1
        for (int c = 0; c < 25; c++) {
            const float* wcc = wrow + c * 9;
            #pragma unroll
            for (int ky = 0; ky < 3; ky++) {
                int yy = y + ky - 1; if (yy < 0 || yy >= 15) continue;
                const float* zr = zs + c * 225 + yy * 15;
                float w0 = __ldg(wcc + ky * 3 + 0), w1 = __ldg(wcc + ky * 3 + 1), w2v = __ldg(wcc + ky * 3 + 2);
                float rv[10];   // cols xb-1 .. xb+8
                #pragma unroll
                for (int u = 0; u < 10; u++) {
                    int col = xb - 1 + u;
                    rv[u] = (col >= 0 && col < 15) ? zr[col] : 0.f;
                }
                #pragma unroll
                for (int xx = 0; xx < 8; xx++)
                    acc[xx] += w0 * rv[xx] + w1 * rv[xx + 1] + w2v * rv[xx + 2];
            }
        }
        float sm = 0.f, sq = 0.f;
        int start = xh;   // half1 skips its col 7 (xx=0) in sums (half0 owns it)
        #pragma unroll
        for (int xx = 0; xx < 8; xx++) {
            float v = acc[xx];
            cbuf[(size_t)s * 5625 + c2 * 225 + y * 15 + xb + xx] = v;  // col7 dup identical
            if (xx >= start) { sm += v; sq += v * v; }
        }
        rowsum[tid] = sm; rowsq[tid] = sq;
    }
    __syncthreads();
    if (tid < 25) {
        float sm = 0.f, sq = 0.f;
        for (int r = tid * 30; r < tid * 30 + 30; r++) { sm += rowsum[r]; sq += rowsq[r]; }
        part[((size_t)s * 25 + tid) * 2] = sm; part[((size_t)s * 25 + tid) * 2 + 1] = sq;
    }
}

__global__ void k_stats2d(const float* part, const float* g, const float* bb, float* par) {
    __shared__ double dred[256];
    int c = blockIdx.x, tid = threadIdx.x;
    double s = 0, q = 0;
    for (int ss = tid; ss < B * L; ss += 256) { s += part[((size_t)ss * 25 + c) * 2]; q += part[((size_t)ss * 25 + c) * 2 + 1]; }
    s = blockSumD(s, dred); q = blockSumD(q, dred);
    if (tid == 0) {
        double N = (double)B * L * SP;
        double mean = s / N, var = q / N - mean * mean;
        float sc = g[c] / (float)sqrt(var + (double)EPS);
        float sh = bb[c] - (float)mean * sc;
        par[48 + c] = sc; par[80 + c] = sh;
    }
}

// ---------------- head: fused final apply + pool + fc1(tanh) + fc2(sigmoid) ----------------
__global__ __launch_bounds__(256) void k_head(const float* __restrict__ z, const float* __restrict__ cbuf,
                      const float* __restrict__ par, const int* __restrict__ xi, const float* __restrict__ emb,
                      const float* __restrict__ fc1T, const float* __restrict__ fc1b,
                      const float* __restrict__ fc2w, const float* __restrict__ fc2b,
                      float* __restrict__ out) {
    __shared__ float feat[450];
    __shared__ float red[4];
    int s = blockIdx.x, tid = threadIdx.x;
    if (tid < 225) {
        float sm = 0.f;
        for (int c = 0; c < 25; c++) {
            size_t o = (size_t)s * 5625 + c * 225 + tid;
            sm += z[o] + fmaxf(par[48 + c] * cbuf[o] + par[80 + c], 0.f);
        }
        feat[tid] = sm * (1.f / 25.f);
        feat[225 + tid] = emb[(size_t)xi[s] * SP + tid];
    }
    __syncthreads();
    float hv = 0.f;
    {
        float acc = (tid < 200) ? fc1b[tid] : 0.f;
        for (int k = 0; k < 450; k++) {
            float wv = (tid < 200) ? fc1T[k * 200 + tid] : 0.f;
            acc += feat[k] * wv;
        }
        if (tid < 200) hv = tanhf(acc) * fc2w[tid];
    }
    float tot = waveRed(hv);
    if ((tid & 63) == 0) red[tid >> 6] = tot;
    __syncthreads();
    if (tid == 0) out[s] = 1.f / (1.f + expf(-(red[0] + red[1] + red[2] + red[3] + fc2b[0])));
}

extern "C" void kernel_launch(void* const* d_in, const int* in_sizes, int n_in,
                              void* d_out, int out_size, void* d_ws, size_t ws_size,
                              hipStream_t stream) {
    const int*   xi   = (const int*)d_in[0];
    const float* emb  = (const float*)d_in[1];
    const float* w3a  = (const float*)d_in[2];
    const float* g3a  = (const float*)d_in[3];
    const float* b3a  = (const float*)d_in[4];
    const float* w3b  = (const float*)d_in[5];
    const float* g3b  = (const float*)d_in[6];
    const float* b3b  = (const float*)d_in[7];
    const float* w3c  = (const float*)d_in[8];
    const float* g3c  = (const float*)d_in[9];
    const float* b3c  = (const float*)d_in[10];
    const float* w3d  = (const float*)d_in[11];
    const float* g3d  = (const float*)d_in[12];
    const float* b3d  = (const float*)d_in[13];
    const float* w2   = (const float*)d_in[14];
    const float* g2   = (const float*)d_in[15];
    const float* b2   = (const float*)d_in[16];
    const float* fc1w = (const float*)d_in[17];
    const float* fc1b = (const float*)d_in[18];
    const float* fc2w = (const float*)d_in[19];
    const float* fc2b = (const float*)d_in[20];
    float* ws = (float*)d_ws;
    float* out = (float*)d_out;
    if (ws_size < WS_FLOATS * sizeof(float)) return;

    float* F1  = ws + OFF_F1;   float* E2  = ws + OFF_E2;  float* E1  = ws + OFF_E1;
    float* SS1 = ws + OFF_SS1;  float* par = ws + OFF_PAR;
    float* F2  = ws + OFF_F2;   float* C2b = ws + OFF_C2;  float* T2  = ws + OFF_T2;
    float* SS2F= ws + OFF_SS2F; float* SS2T= ws + OFF_SS2T; float* SS2C= ws + OFF_SS2C;
    float* F3  = ws + OFF_F3;   float* C3b = ws + OFF_C3;  float* T3  = ws + OFF_T3;
    float* SS3F= ws + OFF_SS3F; float* SS3T= ws + OFF_SS3T; float* SS3C= ws + OFF_SS3C;
    float* F4  = ws + OFF_F4;   float* C4b = ws + OFF_C4;  float* T4  = ws + OFF_T4;
    float* SS4F= ws + OFF_SS4F; float* SS4T= ws + OFF_SS4T; float* SS4C= ws + OFF_SS4C;
    float* z   = ws + OFF_Z;    float* cb  = ws + OFF_CB;  float* p2d = ws + OFF_P2D;
    float* fc1T = ws + OFF_E2;  // E2 dead after k_T2

    k_layer1<<<B * D1, 256, 0, stream>>>(xi, emb, w3a, F1, E2, E1, SS1);
    k_stats1<<<4, 256, 0, stream>>>(SS1, g3a, b3a, par);
    k_F2<<<B * C2N * D2, 256, 0, stream>>>(F1, par, w3b, F2, SS2F);
    k_C2<<<1, 256, 0, stream>>>(par, w3b, C2b, SS2C);
    k_T2<<<B * L, 512, 0, stream>>>(F1, E2, E1, par, w3b, T2, SS2T);
    k_trfc1<<<(90000 + 255) / 256, 256, 0, stream>>>(fc1w, fc1T);
    k_stats2<<<8, 256, 0, stream>>>(SS2F, SS2T, SS2C, g3b, b3b, par);
    k_F3<<<B * C3N * D3, 256, 0, stream>>>(F2, par, w3c, F3, SS3F);
    k_C3<<<1, 256, 0, stream>>>(C2b, par, w3c, C3b, SS3C);
    k_T3<<<B * L, 512, 0, stream>>>(F2, T2, C2b, par, w3c, T3, SS3T);
    k_stats3<<<4, 256, 0, stream>>>(SS3F, SS3T, SS3C, g3c, b3c, par);
    k_F4<<<B * D4, 256, 0, stream>>>(F3, par, w3d, F4, SS4F);
    k_C4<<<1, 256, 0, stream>>>(C3b, par, w3d, C4b, SS4C);
    k_T4<<<B * L, 512, 0, stream>>>(F3, T3, C3b, par, w3d, T4, SS4T);
    k_stats4<<<1, 256, 0, stream>>>(SS4F, SS4T, SS4C, g3d, b3d, par);

    k_conv2d<0><<<B * L, 768, 0, stream>>>(z, z, cb, par, F4, T4, C4b, w2, cb, p2d);
    k_stats2d<<<25, 256, 0, stream>>>(p2d, g2, b2, par);
    for (int it = 1; it < 5; it++) {
        k_conv2d<1><<<B * L, 768, 0, stream>>>(z, z, cb, par, F4, T4, C4b, w2 + (size_t)it * 5625, cb, p2d);
        k_stats2d<<<25, 256, 0, stream>>>(p2d, g2 + it * 25, b2 + it * 25, par);
    }
    k_head<<<B * L, 256, 0, stream>>>(z, cb, par, xi, emb, fc1T, fc1b, fc2w, fc2b, out);
}

// Round 15
// 571.662 us; speedup vs baseline: 1.1802x; 1.1802x over previous
//
#include <hip/hip_runtime.h>
#include <math.h>

#define DEV __device__ __forceinline__

constexpr int B = 4, L = 200, SP = 225;
constexpr int C1 = 4, D1 = 200;
constexpr int C2N = 8, D2 = 100;
constexpr int C3N = 4, D3 = 50;
constexpr int D4 = 25;
constexpr float EPS = 1e-5f;

// ---- workspace layout (float offsets) ----
constexpr size_t OFF_F1  = 0;                      // B*C1*D1*SP raw
constexpr size_t OFF_E2  = OFF_F1  + 720000;       // raw; REUSED as fc1T (90000) after k_T2
constexpr size_t OFF_E1  = OFF_E2  + 720000;
constexpr size_t OFF_SS1 = OFF_E1  + 720000;       // 6*3200
constexpr size_t OFF_PAR = OFF_SS1 + 19200;        // 1024 params
constexpr size_t OFF_F2  = OFF_PAR + 1024;         // raw
constexpr size_t OFF_C2  = OFF_F2  + 720000;       // C2N*SP raw
constexpr size_t OFF_T2  = OFF_C2  + 1800;         // raw
constexpr size_t OFF_SS2F= OFF_T2  + 2880000;
constexpr size_t OFF_SS2T= OFF_SS2F+ 6400;
constexpr size_t OFF_SS2C= OFF_SS2T+ 51200;
constexpr size_t OFF_F3  = OFF_SS2C+ 16;
constexpr size_t OFF_C3  = OFF_F3  + 180000;
constexpr size_t OFF_T3  = OFF_C3  + 900;
constexpr size_t OFF_SS3F= OFF_T3  + 1440000;
constexpr size_t OFF_SS3T= OFF_SS3F+ 1600;
constexpr size_t OFF_SS3C= OFF_SS3T+ 12800;
constexpr size_t OFF_F4  = OFF_SS3C+ 8;
constexpr size_t OFF_C4  = OFF_F4  + 22500;
constexpr size_t OFF_T4  = OFF_C4  + 225;
constexpr size_t OFF_SS4F= OFF_T4  + 360000;
constexpr size_t OFF_SS4T= OFF_SS4F+ 200;
constexpr size_t OFF_SS4C= OFF_SS4T+ 3200;
constexpr size_t OFF_Z   = OFF_SS4C+ 2;            // B*L*25*SP
constexpr size_t OFF_CB  = OFF_Z   + 4500000;
constexpr size_t OFF_P2D = OFF_CB  + 4500000;      // 800*25*2
constexpr size_t WS_FLOATS = OFF_P2D + 40000;

// params: 0..3 sc1, 4..7 sh1, 8..11 z1; 16..23 sc2, 24..31 sh2;
// 32..35 sc3, 36..39 sh3; 40 sc4, 41 sh4; 48..72 sc2d, 80..104 sh2d

DEV float waveRed(float v) {
    #pragma unroll
    for (int m = 32; m; m >>= 1) v += __shfl_xor(v, m, 64);
    return v;
}
DEV double blockSumD(double v, double* red) {
    int tid = threadIdx.x;
    red[tid] = v; __syncthreads();
    for (int s = 128; s > 0; s >>= 1) { if (tid < s) red[tid] += red[tid + s]; __syncthreads(); }
    double r = red[0]; __syncthreads(); return r;
}
DEV float conv9(const float* S, const float* w, int y, int x) {
    float a = 0.f;
    for (int ky = 0; ky < 3; ky++) { int yy = y + ky - 1; if (yy < 0 || yy >= 15) continue;
        for (int kx = 0; kx < 3; kx++) { int xx = x + kx - 1; if (xx < 0 || xx >= 15) continue;
            a += w[ky * 3 + kx] * S[yy * 15 + xx]; } }
    return a;
}
// gather 9-neighborhood of (y,x) from a 15x15 LDS plane into regs
DEV void gather9(const float* Sp, int y, int x, float* s9) {
    #pragma unroll
    for (int ky = 0; ky < 3; ky++) {
        int yy = y + ky - 1; bool oky = (yy >= 0 && yy < 15);
        #pragma unroll
        for (int kx = 0; kx < 3; kx++) {
            int xx = x + kx - 1; bool ok = oky && (xx >= 0 && xx < 15);
            s9[ky * 3 + kx] = ok ? Sp[yy * 15 + xx] : 0.f;
        }
    }
}

// ---------------- layer 1: all 4 channels per block (weights via s_load) ----------------
__global__ __launch_bounds__(256) void k_layer1(const int* __restrict__ xi, const float* __restrict__ emb,
                        const float* __restrict__ w3a, float* F1, float* E2, float* E1, float* SS1) {
    __shared__ float simg[675];
    __shared__ float red[96];   // wave(4) x c(4) x 6
    int blk = blockIdx.x;
    int d = blk % D1; int b = blk / D1;
    int tid = threadIdx.x;
    for (int idx = tid; idx < 675; idx += 256) {
        int t = idx / 225, pos = idx % 225;
        int j = d + t - 1; float v = 0.f;
        if (j >= 0 && j < L) v = emb[(size_t)xi[b * L + j] * SP + pos];
        simg[idx] = v;
    }
    __syncthreads();
    int y = tid / 15, x = tid % 15;
    int w = tid >> 6;
    #pragma unroll 1
    for (int c = 0; c < 4; c++) {
        float f1 = 0.f, e2 = 0.f, e1 = 0.f;
        if (tid < 225) {
            float P0 = conv9(simg,       w3a + c * 27,      y, x);
            float P1 = conv9(simg + 225, w3a + c * 27 + 9,  y, x);
            float P2 = conv9(simg + 450, w3a + c * 27 + 18, y, x);
            f1 = P0 + P1 + P2; e2 = P0 + P1; e1 = P0;
            size_t o = ((size_t)(b * C1 + c) * D1 + d) * SP + tid;
            F1[o] = f1; E2[o] = e2; E1[o] = e1;
        }
        float r0 = waveRed(f1), r1 = waveRed(f1 * f1), r2 = waveRed(e2),
              r3 = waveRed(e2 * e2), r4 = waveRed(e1), r5 = waveRed(e1 * e1);
        if ((tid & 63) == 0) {
            float* rp = red + w * 24 + c * 6;
            rp[0] = r0; rp[1] = r1; rp[2] = r2; rp[3] = r3; rp[4] = r4; rp[5] = r5;
        }
    }
    __syncthreads();
    if (tid < 24) {
        float s = red[tid] + red[24 + tid] + red[48 + tid] + red[72 + tid];
        int c = tid / 6, q = tid % 6;
        SS1[q * 3200 + (b * C1 + c) * D1 + d] = s;
    }
}

__global__ void k_stats1(const float* SS1, const float* g, const float* bb, float* par) {
    __shared__ double dred[256];
    int c = blockIdx.x; int tid = threadIdx.x;
    double s = 0, q = 0;
    for (int idx = tid; idx < B * D1; idx += 256) {
        int b = idx / D1, d = idx % D1;
        int sl = (b * C1 + c) * D1 + d;
        double wF = (double)(L - 1 - d);
        s += wF * SS1[sl] + SS1[6400 + sl] + (d >= 1 ? SS1[12800 + sl] : 0.0);
        q += wF * SS1[3200 + sl] + SS1[9600 + sl] + (d >= 1 ? SS1[16000 + sl] : 0.0);
    }
    s = blockSumD(s, dred); q = blockSumD(q, dred);
    if (tid == 0) {
        double N = (double)B * L * D1 * SP;
        double mean = s / N, var = q / N - mean * mean;
        float sc = g[c] / (float)sqrt(var + (double)EPS);
        float sh = bb[c] - (float)mean * sc;
        par[c] = sc; par[4 + c] = sh; par[8 + c] = fmaxf(sh, 0.f);
    }
}

// ---------------- layer 2 ----------------
__global__ __launch_bounds__(256) void k_F2(const float* __restrict__ F1raw, const float* __restrict__ par,
                        const float* __restrict__ w3b, float* F2, float* SS2F) {
    __shared__ float S[2700];   // [t][c][225]
    __shared__ float red[8];
    int blk = blockIdx.x; int d2 = blk % D2; int c2 = (blk / D2) % C2N; int b = blk / (D2 * C2N);
    int tid = threadIdx.x;
    for (int idx = tid; idx < 2700; idx += 256) {
        int p = idx / 225, pos = idx % 225; int t = p >> 2, c = p & 3;
        int j = 2 * d2 - 1 + t; float v = 0.f;
        if (j >= 0 && j < D1)
            v = fmaxf(par[c] * F1raw[((size_t)(b * C1 + c) * D1 + j) * SP + pos] + par[4 + c], 0.f);
        S[idx] = v;
    }
    __syncthreads();
    float acc = 0.f;
    if (tid < 225) {
        int y = tid / 15, x = tid % 15;
        #pragma unroll 1
        for (int t = 0; t < 3; t++)
            for (int c = 0; c < 4; c++)
                acc += conv9(S + (t * 4 + c) * 225, w3b + c2 * 108 + c * 27 + t * 9, y, x);
        F2[(size_t)blk * SP + tid] = acc;
    }
    float sm = waveRed(acc), sq = waveRed(acc * acc);
    if ((tid & 63) == 0) { red[(tid >> 6) * 2] = sm; red[(tid >> 6) * 2 + 1] = sq; }
    __syncthreads();
    if (tid == 0) { SS2F[blk] = red[0] + red[2] + red[4] + red[6]; SS2F[3200 + blk] = red[1] + red[3] + red[5] + red[7]; }
}

__global__ void k_C2(const float* __restrict__ par, const float* __restrict__ w3b, float* C2b, float* SS2C) {
    __shared__ float red[64];   // wave(4) x c2(8) x 2
    int tid = threadIdx.x; int y = tid / 15, x = tid % 15; int w = tid >> 6;
    #pragma unroll 1
    for (int c2 = 0; c2 < C2N; c2++) {
        float acc = 0.f;
        if (tid < 225) {
            for (int c = 0; c < C1; c++) {
                float z1 = par[8 + c];
                for (int t = 0; t < 3; t++) {
                    float ws = 0.f;
                    for (int ky = 0; ky < 3; ky++) { int yy = y + ky - 1; if (yy < 0 || yy >= 15) continue;
                        for (int kx = 0; kx < 3; kx++) { int xx = x + kx - 1; if (xx < 0 || xx >= 15) continue;
                            ws += w3b[c2 * 108 + c * 27 + t * 9 + ky * 3 + kx]; } }
                    acc += z1 * ws;
                }
            }
            C2b[c2 * SP + tid] = acc;
        }
        float sm = waveRed(acc), sq = waveRed(acc * acc);
        if ((tid & 63) == 0) { red[w * 16 + c2 * 2] = sm; red[w * 16 + c2 * 2 + 1] = sq; }
    }
    __syncthreads();
    if (tid < 16) SS2C[tid] = red[tid] + red[16 + tid] + red[32 + tid] + red[48 + tid];
}

// 512 threads: group g=tid>>8 computes transition k=g; weights from global (L1/K$).
__global__ __launch_bounds__(512) void k_T2(const float* __restrict__ F1raw, const float* __restrict__ E2raw,
                    const float* __restrict__ E1raw, const float* __restrict__ par,
                    const float* __restrict__ w3b, float* T2, float* SS2T) {
    __shared__ float S[4500];   // [sl 0..4][c 0..3][225]
    __shared__ float red[128];  // 8 waves x 8 c2 x 2
    int blk = blockIdx.x; int i = blk % L, b = blk / L; int tid = threadIdx.x;
    int t2a = i >> 1, jbase = 2 * t2a - 1;
    for (int idx = tid; idx < 4500; idx += 512) {
        int p = idx / 225, pos = idx % 225; int sl = p >> 2, c = p & 3;
        int j = jbase + sl; float v = 0.f;
        if (j >= 0 && j < L) {
            if (j <= i - 1)      v = fmaxf(par[c] * F1raw[((size_t)(b * C1 + c) * D1 + j) * SP + pos] + par[4 + c], 0.f);
            else if (j == i)     v = fmaxf(par[c] * E2raw[((size_t)(b * C1 + c) * D1 + j) * SP + pos] + par[4 + c], 0.f);
            else if (j == i + 1) v = fmaxf(par[c] * E1raw[((size_t)(b * C1 + c) * D1 + j) * SP + pos] + par[4 + c], 0.f);
            else                 v = par[8 + c];
        }
        S[idx] = v;
    }
    __syncthreads();
    int g = tid >> 8;            // k = g
    int tp = tid & 255;
    int y = tp / 15, x = tp % 15;
    float vals[8] = {0,0,0,0,0,0,0,0};
    int d2 = t2a + g;
    if (d2 < D2 && tp < 225) {
        #pragma unroll 1
        for (int t = 0; t < 3; t++) {
            int sl = 2 * g + t;
            #pragma unroll 1
            for (int c = 0; c < 4; c++) {
                float s9[9];
                gather9(S + (sl * 4 + c) * 225, y, x, s9);
                const float* wb = w3b + c * 27 + t * 9;   // uniform -> s_load
                #pragma unroll
                for (int c2 = 0; c2 < 8; c2++) {
                    const float* wc = wb + c2 * 108;
                    float a = 0.f;
                    #pragma unroll
                    for (int q = 0; q < 9; q++) a += wc[q] * s9[q];
                    vals[c2] += a;
                }
            }
        }
    }
    if (tp < 225)
        #pragma unroll
        for (int c2 = 0; c2 < 8; c2++) T2[(((size_t)blk * 2 + g) * C2N + c2) * SP + tp] = vals[c2];
    int w = tid >> 6;   // 0..7
    #pragma unroll
    for (int c2 = 0; c2 < 8; c2++) {
        float sm = waveRed(tp < 225 ? vals[c2] : 0.f), sq = waveRed(tp < 225 ? vals[c2] * vals[c2] : 0.f);
        if ((tid & 63) == 0) { red[w * 16 + c2 * 2] = sm; red[w * 16 + c2 * 2 + 1] = sq; }
    }
    __syncthreads();
    if (tid < 32) {
        int k = tid >> 4, idx = tid & 15;
        int c2 = idx >> 1, q = idx & 1;
        int wb = k * 4;
        float s = red[(wb + 0) * 16 + idx] + red[(wb + 1) * 16 + idx]
                + red[(wb + 2) * 16 + idx] + red[(wb + 3) * 16 + idx];
        (q ? SS2T + 25600 : SS2T)[((size_t)blk * 2 + k) * C2N + c2] = s;
    }
}

// closed-form multiplicities: F slice (b,d2) counted (L-2*d2-2)x; T entries once each
// (invalid entries are exact zeros); C counted sum_i max(0, D2-(i>>1)-2) per b.
__global__ void k_stats2(const float* SS2F, const float* SS2T, const float* SS2C,
                         const float* g, const float* bb, float* par) {
    __shared__ double dred[256];
    int c2 = blockIdx.x; int tid = threadIdx.x;
    double s = 0, q = 0;
    for (int idx = tid; idx < B * D2; idx += 256) {
        int d2 = idx % D2; int b = idx / D2;
        int wv = L - 2 * d2 - 2; if (wv < 0) wv = 0;
        int sl = (b * C2N + c2) * D2 + d2;
        s += (double)wv * SS2F[sl]; q += (double)wv * SS2F[3200 + sl];
    }
    for (int idx = tid; idx < B * L * 2; idx += 256) {
        int sl = idx * C2N + c2;
        s += SS2T[sl]; q += SS2T[25600 + sl];
    }
    {
        int cnt = 0;
        for (int i = tid; i < L; i += 256) { int v = D2 - (i >> 1) - 2; if (v > 0) cnt += v; }
        double wv = (double)cnt * B;
        s += wv * SS2C[c2 * 2]; q += wv * SS2C[c2 * 2 + 1];
    }
    s = blockSumD(s, dred); q = blockSumD(q, dred);
    if (tid == 0) {
        double N = (double)B * L * D2 * SP;
        double mean = s / N, var = q / N - mean * mean;
        float sc = g[c2] / (float)sqrt(var + (double)EPS);
        float sh = bb[c2] - (float)mean * sc;
        par[16 + c2] = sc; par[24 + c2] = sh;
    }
}

// ---------------- layer 3 ----------------
__global__ __launch_bounds__(256) void k_F3(const float* __restrict__ F2raw, const float* __restrict__ par,
                        const float* __restrict__ w3c, float* F3, float* SS3F) {
    __shared__ float S[5400];   // [t][c2][225]
    __shared__ float red[8];
    int blk = blockIdx.x; int d3 = blk % D3; int c3 = (blk / D3) % C3N; int b = blk / (D3 * C3N);
    int tid = threadIdx.x;
    for (int idx = tid; idx < 5400; idx += 256) {
        int p = idx / 225, pos = idx % 225; int t = p >> 3, c2 = p & 7;
        int j2 = 2 * d3 - 1 + t; float v = 0.f;
        if (j2 >= 0 && j2 < D2)
            v = fmaxf(par[16 + c2] * F2raw[((size_t)(b * C2N + c2) * D2 + j2) * SP + pos] + par[24 + c2], 0.f);
        S[idx] = v;
    }
    __syncthreads();
    float acc = 0.f;
    if (tid < 225) {
        int y = tid / 15, x = tid % 15;
        #pragma unroll 1
        for (int t = 0; t < 3; t++)
            for (int c2 = 0; c2 < 8; c2++)
                acc += conv9(S + (t * 8 + c2) * 225, w3c + c3 * 216 + c2 * 27 + t * 9, y, x);
        F3[(size_t)blk * SP + tid] = acc;
    }
    float sm = waveRed(acc), sq = waveRed(acc * acc);
    if ((tid & 63) == 0) { red[(tid >> 6) * 2] = sm; red[(tid >> 6) * 2 + 1] = sq; }
    __syncthreads();
    if (tid == 0) { SS3F[blk] = red[0] + red[2] + red[4] + red[6]; SS3F[800 + blk] = red[1] + red[3] + red[5] + red[7]; }
}

__global__ void k_C3(const float* __restrict__ C2braw, const float* __restrict__ par,
                     const float* __restrict__ w3c, float* C3b, float* SS3C) {
    __shared__ float S[1800];
    __shared__ float red[32];   // wave(4) x c3(4) x 2
    int tid = threadIdx.x; int w = tid >> 6;
    for (int idx = tid; idx < 1800; idx += 256) {
        int c2 = idx / 225;
        S[idx] = fmaxf(par[16 + c2] * C2braw[idx] + par[24 + c2], 0.f);
    }
    __syncthreads();
    int y = tid / 15, x = tid % 15;
    #pragma unroll 1
    for (int c3 = 0; c3 < C3N; c3++) {
        float acc = 0.f;
        if (tid < 225) {
            for (int t = 0; t < 3; t++)
                for (int c2 = 0; c2 < C2N; c2++)
                    acc += conv9(S + c2 * 225, w3c + c3 * 216 + c2 * 27 + t * 9, y, x);
            C3b[c3 * SP + tid] = acc;
        }
        float sm = waveRed(acc), sq = waveRed(acc * acc);
        if ((tid & 63) == 0) { red[w * 8 + c3 * 2] = sm; red[w * 8 + c3 * 2 + 1] = sq; }
    }
    __syncthreads();
    if (tid < 8) SS3C[tid] = red[tid] + red[8 + tid] + red[16 + tid] + red[24 + tid];
}

// 512 threads: group g=tid>>8 computes transition k=g; weights from global (L1/K$).
__global__ __launch_bounds__(512) void k_T3(const float* __restrict__ F2raw, const float* __restrict__ T2raw,
                    const float* __restrict__ C2braw, const float* __restrict__ par,
                    const float* __restrict__ w3c, float* T3, float* SS3T) {
    __shared__ float S[9000];   // [sl 0..4][c2 0..7][225]
    __shared__ float red[64];   // 8 waves x 4 c3 x 2
    int blk = blockIdx.x; int i = blk % L, b = blk / L; int tid = threadIdx.x;
    int t2a = i >> 1, t3a = i >> 2, j2base = 2 * t3a - 1;
    for (int idx = tid; idx < 9000; idx += 512) {
        int p = idx / 225, pos = idx % 225; int sl = p >> 3, c2 = p & 7;
        int j2 = j2base + sl; float v = 0.f;
        if (j2 >= 0 && j2 < D2) {
            float raw;
            if (j2 < t2a)           raw = F2raw[((size_t)(b * C2N + c2) * D2 + j2) * SP + pos];
            else if (j2 == t2a)     raw = T2raw[(((size_t)blk * 2 + 0) * C2N + c2) * SP + pos];
            else if (j2 == t2a + 1) raw = T2raw[(((size_t)blk * 2 + 1) * C2N + c2) * SP + pos];
            else                    raw = C2braw[c2 * SP + pos];
            v = fmaxf(par[16 + c2] * raw + par[24 + c2], 0.f);
        }
        S[idx] = v;
    }
    __syncthreads();
    int g = tid >> 8;            // k = g
    int tp = tid & 255;
    int y = tp / 15, x = tp % 15;
    float vals[4] = {0, 0, 0, 0};
    int d3 = t3a + g;
    if (d3 < D3 && tp < 225) {
        #pragma unroll 1
        for (int t = 0; t < 3; t++) {
            int sl = 2 * g + t;
            #pragma unroll 1
            for (int c2 = 0; c2 < 8; c2++) {
                float s9[9];
                gather9(S + (sl * 8 + c2) * 225, y, x, s9);
                const float* wb = w3c + c2 * 27 + t * 9;   // uniform -> s_load
                #pragma unroll
                for (int c3 = 0; c3 < 4; c3++) {
                    const float* wc = wb + c3 * 216;
                    float a = 0.f;
                    #pragma unroll
                    for (int q = 0; q < 9; q++) a += wc[q] * s9[q];
                    vals[c3] += a;
                }
            }
        }
    }
    if (tp < 225)
        #pragma unroll
        for (int c3 = 0; c3 < 4; c3++) T3[(((size_t)blk * 2 + g) * C3N + c3) * SP + tp] = vals[c3];
    int w = tid >> 6;   // 0..7
    #pragma unroll
    for (int c3 = 0; c3 < 4; c3++) {
        float sm = waveRed(tp < 225 ? vals[c3] : 0.f), sq = waveRed(tp < 225 ? vals[c3] * vals[c3] : 0.f);
        if ((tid & 63) == 0) { red[w * 8 + c3 * 2] = sm; red[w * 8 + c3 * 2 + 1] = sq; }
    }
    __syncthreads();
    if (tid < 16) {
        int k = tid >> 3, idx = tid & 7;
        int c3 = idx >> 1, q = idx & 1;
        int wb = k * 4;
        float s = red[(wb + 0) * 8 + idx] + red[(wb + 1) * 8 + idx]
                + red[(wb + 2) * 8 + idx] + red[(wb + 3) * 8 + idx];
        (q ? SS3T + 6400 : SS3T)[((size_t)blk * 2 + k) * C3N + c3] = s;
    }
}

__global__ void k_stats3(const float* SS3F, const float* SS3T, const float* SS3C,
                         const float* g, const float* bb, float* par) {
    __shared__ double dred[256];
    int c3 = blockIdx.x; int tid = threadIdx.x;
    double s = 0, q = 0;
    for (int idx = tid; idx < B * D3; idx += 256) {
        int d3 = idx % D3; int b = idx / D3;
        int wv = L - 4 * d3 - 4; if (wv < 0) wv = 0;
        int sl = (b * C3N + c3) * D3 + d3;
        s += (double)wv * SS3F[sl]; q += (double)wv * SS3F[800 + sl];
    }
    for (int idx = tid; idx < B * L * 2; idx += 256) {
        int sl = idx * C3N + c3;
        s += SS3T[sl]; q += SS3T[6400 + sl];
    }
    {
        int cnt = 0;
        for (int i = tid; i < L; i += 256) { int v = D3 - (i >> 2) - 2; if (v > 0) cnt += v; }
        double wv = (double)cnt * B;
        s += wv * SS3C[c3 * 2]; q += wv * SS3C[c3 * 2 + 1];
    }
    s = blockSumD(s, dred); q = blockSumD(q, dred);
    if (tid == 0) {
        double N = (double)B * L * D3 * SP;
        double mean = s / N, var = q / N - mean * mean;
        float sc = g[c3] / (float)sqrt(var + (double)EPS);
        float sh = bb[c3] - (float)mean * sc;
        par[32 + c3] = sc; par[36 + c3] = sh;
    }
}

// ---------------- layer 4 ----------------
__global__ __launch_bounds__(256) void k_F4(const float* __restrict__ F3raw, const float* __restrict__ par,
                        const float* __restrict__ w3d, float* F4, float* SS4F) {
    __shared__ float S[2700];   // [t][c3][225]
    __shared__ float red[8];
    int blk = blockIdx.x; int d4 = blk % D4; int b = blk / D4; int tid = threadIdx.x;
    for (int idx = tid; idx < 2700; idx += 256) {
        int p = idx / 225, pos = idx % 225; int t = p >> 2, c3 = p & 3;
        int j3 = 2 * d4 - 1 + t; float v = 0.f;
        if (j3 >= 0 && j3 < D3)
            v = fmaxf(par[32 + c3] * F3raw[((size_t)(b * C3N + c3) * D3 + j3) * SP + pos] + par[36 + c3], 0.f);
        S[idx] = v;
    }
    __syncthreads();
    float acc = 0.f;
    if (tid < 225) {
        int y = tid / 15, x = tid % 15;
        #pragma unroll 1
        for (int t = 0; t < 3; t++)
            for (int c3 = 0; c3 < 4; c3++)
                acc += conv9(S + (t * 4 + c3) * 225, w3d + c3 * 27 + t * 9, y, x);
        F4[(size_t)blk * SP + tid] = acc;
    }
    float sm = waveRed(acc), sq = waveRed(acc * acc);
    if ((tid & 63) == 0) { red[(tid >> 6) * 2] = sm; red[(tid >> 6) * 2 + 1] = sq; }
    __syncthreads();
    if (tid == 0) { SS4F[blk] = red[0] + red[2] + red[4] + red[6]; SS4F[100 + blk] = red[1] + red[3] + red[5] + red[7]; }
}

__global__ void k_C4(const float* __restrict__ C3braw, const float* __restrict__ par,
                     const float* __restrict__ w3d, float* C4b, float* SS4C) {
    __shared__ float S[900];
    __shared__ float red[8];
    int tid = threadIdx.x;
    for (int idx = tid; idx < 900; idx += 256) {
        int c3 = idx / 225;
        S[idx] = fmaxf(par[32 + c3] * C3braw[idx] + par[36 + c3], 0.f);
    }
    __syncthreads();
    int y = tid / 15, x = tid % 15;
    float acc = 0.f;
    if (tid < 225) {
        for (int t = 0; t < 3; t++)
            for (int c3 = 0; c3 < C3N; c3++)
                acc += conv9(S + c3 * 225, w3d + c3 * 27 + t * 9, y, x);
        C4b[tid] = acc;
    }
    float sm = waveRed(acc), sq = waveRed(acc * acc);
    if ((tid & 63) == 0) { red[(tid >> 6) * 2] = sm; red[(tid >> 6) * 2 + 1] = sq; }
    __syncthreads();
    if (tid == 0) { SS4C[0] = red[0] + red[2] + red[4] + red[6]; SS4C[1] = red[1] + red[3] + red[5] + red[7]; }
}

// 512 threads: group g=tid>>8 computes transition k=g; weights from global (L1/K$).
__global__ __launch_bounds__(512) void k_T4(const float* __restrict__ F3raw, const float* __restrict__ T3raw,
                    const float* __restrict__ C3braw, const float* __restrict__ par,
                    const float* __restrict__ w3d, float* T4, float* SS4T) {
    __shared__ float S[4500];   // [sl][c3][225]
    __shared__ float red[16];   // 8 waves x 2
    int blk = blockIdx.x; int i = blk % L, b = blk / L; int tid = threadIdx.x;
    int t3a = i >> 2, t4a = i >> 3, j3base = 2 * t4a - 1;
    for (int idx = tid; idx < 4500; idx += 512) {
        int p = idx / 225, pos = idx % 225; int sl = p >> 2, c3 = p & 3;
        int j3 = j3base + sl; float v = 0.f;
        if (j3 >= 0 && j3 < D3) {
            float raw;
            if (j3 < t3a)           raw = F3raw[((size_t)(b * C3N + c3) * D3 + j3) * SP + pos];
            else if (j3 == t3a)     raw = T3raw[(((size_t)blk * 2 + 0) * C3N + c3) * SP + pos];
            else if (j3 == t3a + 1) raw = T3raw[(((size_t)blk * 2 + 1) * C3N + c3) * SP + pos];
            else                    raw = C3braw[c3 * SP + pos];
            v = fmaxf(par[32 + c3] * raw + par[36 + c3], 0.f);
        }
        S[idx] = v;
    }
    __syncthreads();
    int g = tid >> 8;            // k = g
    int tp = tid & 255;
    int y = tp / 15, x = tp % 15;
    float acc = 0.f;
    int d4 = t4a + g;
    if (d4 < D4 && tp < 225) {
        #pragma unroll 1
        for (int t = 0; t < 3; t++) {
            int sl = 2 * g + t;
            #pragma unroll 1
            for (int c3 = 0; c3 < 4; c3++) {
                float s9[9];
                gather9(S + (sl * 4 + c3) * 225, y, x, s9);
                const float* wc = w3d + c3 * 27 + t * 9;   // uniform -> s_load
                float a = 0.f;
                #pragma unroll
                for (int q = 0; q < 9; q++) a += wc[q] * s9[q];
                acc += a;
            }
        }
    }
    if (tp < 225) T4[((size_t)blk * 2 + g) * SP + tp] = acc;
    int w = tid >> 6;
    float sm = waveRed(tp < 225 ? acc : 0.f), sq = waveRed(tp < 225 ? acc * acc : 0.f);
    if ((tid & 63) == 0) { red[w * 2] = sm; red[w * 2 + 1] = sq; }
    __syncthreads();
    if (tid < 4) {
        int k = tid >> 1, q = tid & 1;
        int wb = k * 4;
        float s = red[(wb + 0) * 2 + q] + red[(wb + 1) * 2 + q] + red[(wb + 2) * 2 + q] + red[(wb + 3) * 2 + q];
        (q ? SS4T + 1600 : SS4T)[blk * 2 + k] = s;
    }
}

__global__ void k_stats4(const float* SS4F, const float* SS4T, const float* SS4C,
                         const float* g, const float* bb, float* par) {
    __shared__ double dred[256];
    int tid = threadIdx.x; double s = 0, q = 0;
    for (int idx = tid; idx < B * D4; idx += 256) {
        int d4 = idx % D4; int b = idx / D4;
        int wv = L - 8 * d4 - 8; if (wv < 0) wv = 0;
        s += (double)wv * SS4F[b * D4 + d4]; q += (double)wv * SS4F[100 + b * D4 + d4];
    }
    for (int idx = tid; idx < B * L * 2; idx += 256) {
        s += SS4T[idx]; q += SS4T[1600 + idx];
    }
    {
        int cnt = 0;
        for (int i = tid; i < L; i += 256) { int v = D4 - (i >> 3) - 2; if (v > 0) cnt += v; }
        double wv = (double)cnt * B;
        s += wv * SS4C[0]; q += wv * SS4C[1];
    }
    s = blockSumD(s, dred); q = blockSumD(q, dred);
    if (tid == 0) {
        double N = (double)B * L * D4 * SP;
        double mean = s / N, var = q / N - mean * mean;
        float sc = g[0] / (float)sqrt(var + (double)EPS);
        float sh = bb[0] - (float)mean * sc;
        par[40] = sc; par[41] = sh;
    }
}

// ---------------- fc1 weight transpose (into dead E2 region) ----------------
__global__ void k_trfc1(const float* __restrict__ fc1w, float* __restrict__ fc1T) {
    int idx = blockIdx.x * 256 + threadIdx.x;
    if (idx >= 200 * 450) return;
    int o = idx % 200, k = idx / 200;
    fc1T[idx] = fc1w[(size_t)o * 450 + k];
}

// ---------------- 2D residual conv loop (r12/r13 proven best: 384 thr, global weights) ----------------
template<int MODE>
__global__ __launch_bounds__(384) void k_conv2d(const float* __restrict__ zin, float* __restrict__ zout,
        const float* __restrict__ cprev, const float* __restrict__ par,
        const float* __restrict__ F4s, const float* __restrict__ T4s, const float* __restrict__ C4s,
        const float* __restrict__ w2it, float* __restrict__ cbuf, float* __restrict__ part) {
    __shared__ float zs[5625];    // unpadded: stride 15 -> conflict-free
    __shared__ float rowsum[375], rowsq[375];
    int s = blockIdx.x, tid = threadIdx.x;
    int i = s % L, b = s / L; int t4a = i >> 3;
    for (int idx = tid; idx < 5625; idx += 384) {
        int c = idx / 225, pos = idx % 225;
        float v;
        if (MODE == 0) {
            float raw;
            if (c < t4a)           raw = F4s[((size_t)b * D4 + c) * SP + pos];
            else if (c == t4a)     raw = T4s[((size_t)s * 2 + 0) * SP + pos];
            else if (c == t4a + 1) raw = T4s[((size_t)s * 2 + 1) * SP + pos];
            else                   raw = C4s[pos];
            v = fmaxf(par[40] * raw + par[41], 0.f);
        } else {
            v = zin[(size_t)s * 5625 + idx] + fmaxf(par[48 + c] * cprev[(size_t)s * 5625 + idx] + par[80 + c], 0.f);
        }
        zout[(size_t)s * 5625 + idx] = v;
        zs[idx] = v;
    }
    __syncthreads();
    if (tid < 375) {
        int c2 = tid / 15, y = tid % 15;
        float acc[15];
        #pragma unroll
        for (int xx = 0; xx < 15; xx++) acc[xx] = 0.f;
        const float* wrow = w2it + c2 * 225;
        #pragma unroll 1
        for (int c = 0; c < 25; c++) {
            const float* wcc = wrow + c * 9;
            #pragma unroll
            for (int ky = 0; ky < 3; ky++) {
                int yy = y + ky - 1; if (yy < 0 || yy >= 15) continue;
                const float* zr = zs + c * 225 + yy * 15;
                float w0 = __ldg(wcc + ky * 3 + 0), w1 = __ldg(wcc + ky * 3 + 1), w2v = __ldg(wcc + ky * 3 + 2);
                float rv[15];
                #pragma unroll
                for (int xx = 0; xx < 15; xx++) rv[xx] = zr[xx];
                acc[0] += w1 * rv[0] + w2v * rv[1];
                #pragma unroll
                for (int xx = 1; xx < 14; xx++) acc[xx] += w0 * rv[xx - 1] + w1 * rv[xx] + w2v * rv[xx + 1];
                acc[14] += w0 * rv[13] + w1 * rv[14];
            }
        }
        float sm = 0.f, sq = 0.f;
        #pragma unroll
        for (int xx = 0; xx < 15; xx++) {
            float v = acc[xx]; sm += v; sq += v * v;
            cbuf[(size_t)s * 5625 + tid * 15 + xx] = v;
        }
        rowsum[tid] = sm; rowsq[tid] = sq;
    }
    __syncthreads();
    if (tid < 25) {
        float sm = 0.f, sq = 0.f;
        for (int r = tid * 15; r < tid * 15 + 15; r++) { sm += rowsum[r]; sq += rowsq[r]; }
        part[((size_t)s * 25 + tid) * 2] = sm; part[((size_t)s * 25 + tid) * 2 + 1] = sq;
    }
}

__global__ void k_stats2d(const float* part, const float* g, const float* bb, float* par) {
    __shared__ double dred[256];
    int c = blockIdx.x, tid = threadIdx.x;
    double s = 0, q = 0;
    for (int ss = tid; ss < B * L; ss += 256) { s += part[((size_t)ss * 25 + c) * 2]; q += part[((size_t)ss * 25 + c) * 2 + 1]; }
    s = blockSumD(s, dred); q = blockSumD(q, dred);
    if (tid == 0) {
        double N = (double)B * L * SP;
        double mean = s / N, var = q / N - mean * mean;
        float sc = g[c] / (float)sqrt(var + (double)EPS);
        float sh = bb[c] - (float)mean * sc;
        par[48 + c] = sc; par[80 + c] = sh;
    }
}

// ---------------- head: fused final apply + pool + fc1(tanh) + fc2(sigmoid) ----------------
__global__ __launch_bounds__(256) void k_head(const float* __restrict__ z, const float* __restrict__ cbuf,
                      const float* __restrict__ par, const int* __restrict__ xi, const float* __restrict__ emb,
                      const float* __restrict__ fc1T, const float* __restrict__ fc1b,
                      const float* __restrict__ fc2w, const float* __restrict__ fc2b,
                      float* __restrict__ out) {
    __shared__ float feat[450];
    __shared__ float red[4];
    int s = blockIdx.x, tid = threadIdx.x;
    if (tid < 225) {
        float sm = 0.f;
        for (int c = 0; c < 25; c++) {
            size_t o = (size_t)s * 5625 + c * 225 + tid;
            sm += z[o] + fmaxf(par[48 + c] * cbuf[o] + par[80 + c], 0.f);
        }
        feat[tid] = sm * (1.f / 25.f);
        feat[225 + tid] = emb[(size_t)xi[s] * SP + tid];
    }
    __syncthreads();
    float hv = 0.f;
    {
        float acc = (tid < 200) ? fc1b[tid] : 0.f;
        for (int k = 0; k < 450; k++) {
            float wv = (tid < 200) ? fc1T[k * 200 + tid] : 0.f;
            acc += feat[k] * wv;
        }
        if (tid < 200) hv = tanhf(acc) * fc2w[tid];
    }
    float tot = waveRed(hv);
    if ((tid & 63) == 0) red[tid >> 6] = tot;
    __syncthreads();
    if (tid == 0) out[s] = 1.f / (1.f + expf(-(red[0] + red[1] + red[2] + red[3] + fc2b[0])));
}

extern "C" void kernel_launch(void* const* d_in, const int* in_sizes, int n_in,
                              void* d_out, int out_size, void* d_ws, size_t ws_size,
                              hipStream_t stream) {
    const int*   xi   = (const int*)d_in[0];
    const float* emb  = (const float*)d_in[1];
    const float* w3a  = (const float*)d_in[2];
    const float* g3a  = (const float*)d_in[3];
    const float* b3a  = (const float*)d_in[4];
    const float* w3b  = (const float*)d_in[5];
    const float* g3b  = (const float*)d_in[6];
    const float* b3b  = (const float*)d_in[7];
    const float* w3c  = (const float*)d_in[8];
    const float* g3c  = (const float*)d_in[9];
    const float* b3c  = (const float*)d_in[10];
    const float* w3d  = (const float*)d_in[11];
    const float* g3d  = (const float*)d_in[12];
    const float* b3d  = (const float*)d_in[13];
    const float* w2   = (const float*)d_in[14];
    const float* g2   = (const float*)d_in[15];
    const float* b2   = (const float*)d_in[16];
    const float* fc1w = (const float*)d_in[17];
    const float* fc1b = (const float*)d_in[18];
    const float* fc2w = (const float*)d_in[19];
    const float* fc2b = (const float*)d_in[20];
    float* ws = (float*)d_ws;
    float* out = (float*)d_out;
    if (ws_size < WS_FLOATS * sizeof(float)) return;

    float* F1  = ws + OFF_F1;   float* E2  = ws + OFF_E2;  float* E1  = ws + OFF_E1;
    float* SS1 = ws + OFF_SS1;  float* par = ws + OFF_PAR;
    float* F2  = ws + OFF_F2;   float* C2b = ws + OFF_C2;  float* T2  = ws + OFF_T2;
    float* SS2F= ws + OFF_SS2F; float* SS2T= ws + OFF_SS2T; float* SS2C= ws + OFF_SS2C;
    float* F3  = ws + OFF_F3;   float* C3b = ws + OFF_C3;  float* T3  = ws + OFF_T3;
    float* SS3F= ws + OFF_SS3F; float* SS3T= ws + OFF_SS3T; float* SS3C= ws + OFF_SS3C;
    float* F4  = ws + OFF_F4;   float* C4b = ws + OFF_C4;  float* T4  = ws + OFF_T4;
    float* SS4F= ws + OFF_SS4F; float* SS4T= ws + OFF_SS4T; float* SS4C= ws + OFF_SS4C;
    float* z   = ws + OFF_Z;    float* cb  = ws + OFF_CB;  float* p2d = ws + OFF_P2D;
    float* fc1T = ws + OFF_E2;  // E2 dead after k_T2

    k_layer1<<<B * D1, 256, 0, stream>>>(xi, emb, w3a, F1, E2, E1, SS1);
    k_stats1<<<4, 256, 0, stream>>>(SS1, g3a, b3a, par);
    k_F2<<<B * C2N * D2, 256, 0, stream>>>(F1, par, w3b, F2, SS2F);
    k_C2<<<1, 256, 0, stream>>>(par, w3b, C2b, SS2C);
    k_T2<<<B * L, 512, 0, stream>>>(F1, E2, E1, par, w3b, T2, SS2T);
    k_trfc1<<<(90000 + 255) / 256, 256, 0, stream>>>(fc1w, fc1T);
    k_stats2<<<8, 256, 0, stream>>>(SS2F, SS2T, SS2C, g3b, b3b, par);
    k_F3<<<B * C3N * D3, 256, 0, stream>>>(F2, par, w3c, F3, SS3F);
    k_C3<<<1, 256, 0, stream>>>(C2b, par, w3c, C3b, SS3C);
    k_T3<<<B * L, 512, 0, stream>>>(F2, T2, C2b, par, w3c, T3, SS3T);
    k_stats3<<<4, 256, 0, stream>>>(SS3F, SS3T, SS3C, g3c, b3c, par);
    k_F4<<<B * D4, 256, 0, stream>>>(F3, par, w3d, F4, SS4F);
    k_C4<<<1, 256, 0, stream>>>(C3b, par, w3d, C4b, SS4C);
    k_T4<<<B * L, 512, 0, stream>>>(F3, T3, C3b, par, w3d, T4, SS4T);
    k_stats4<<<1, 256, 0, stream>>>(SS4F, SS4T, SS4C, g3d, b3d, par);

    k_conv2d<0><<<B * L, 384, 0, stream>>>(z, z, cb, par, F4, T4, C4b, w2, cb, p2d);
    k_stats2d<<<25, 256, 0, stream>>>(p2d, g2, b2, par);
    for (int it = 1; it < 5; it++) {
        k_conv2d<1><<<B * L, 384, 0, stream>>>(z, z, cb, par, F4, T4, C4b, w2 + (size_t)it * 5625, cb, p2d);
        k_stats2d<<<25, 256, 0, stream>>>(p2d, g2 + it * 25, b2 + it * 25, par);
    }
    k_head<<<B * L, 256, 0, stream>>>(z, cb, par, xi, emb, fc1T, fc1b, fc2w, fc2b, out);
}